// Round 12
// baseline (459.576 us; speedup 1.0000x reference)
//
#include <hip/hip_runtime.h>
#include <stdint.h>

// ---------- types ----------
typedef __attribute__((ext_vector_type(8))) short bf16x8;   // 8 bf16 in 4 VGPRs
typedef __attribute__((ext_vector_type(4))) float f32x4;

__device__ __forceinline__ float bf2f(short u){
  union { float f; uint32_t i; } v; v.i = ((uint32_t)(uint16_t)u) << 16; return v.f;
}
__device__ __forceinline__ short f2bf(float x){
  union { float f; uint32_t i; } v; v.f = x;
  uint32_t r = v.i + 0x7FFFu + ((v.i >> 16) & 1u);   // RNE
  return (short)(r >> 16);
}

// async global->LDS, 16B per lane; LDS dest = wave-uniform base + lane*16
__device__ __forceinline__ void gl_lds16(const short* g, short* l){
  __builtin_amdgcn_global_load_lds(
      (__attribute__((address_space(1))) void*)(short*)g,
      (__attribute__((address_space(3))) void*)l, 16, 0, 0);
}

// ---------- permutation tables (WIN=7, compile-time) ----------
__device__ const int d_DIAG[49] = {0,1,7,2,8,14,3,9,15,21,4,10,16,22,28,5,11,17,23,29,35,
  6,12,18,24,30,36,42,13,19,25,31,37,43,20,26,32,38,44,27,33,39,45,34,40,46,41,47,48};
__device__ const int d_ANTI[49] = {6,5,13,4,12,20,3,11,19,27,2,10,18,26,34,1,9,17,25,33,41,
  0,8,16,24,32,40,48,7,15,23,31,39,47,14,22,30,38,46,21,29,37,45,28,36,44,35,43,42};

__device__ __forceinline__ int perm_idx(int g, int l){
  if (g == 0) return l;
  if (g == 1) return (l % 7) * 7 + l / 7;  // V_IDX
  if (g == 2) return d_DIAG[l];
  return d_ANTI[l];
}

// ---------- 256x128 K-loop core: BK=32, 8 waves (4M x 2N), 48KB LDS ----------
// (proven r6/r11) LDS buffer stride 12288 shorts: A [256r][32] at +0, B [128r][32]
// at +8192. Counted vmcnt(2), 2 barriers/tile. Chunk XOR-swizzle both-sides.
template<int NT>
__device__ __forceinline__ void kcore256x128(
    const short* aU0, const short* aU1, const short* bU,
    short* S, int w, int lane, f32x4 acc[4][4])
{
  int wr = w >> 1, wc = w & 1;
  int mr = lane & 15, quad = lane >> 4;
  int sw = (quad ^ ((mr >> 1) & 3)) * 8;     // swizzled chunk offset (shorts)
  auto STAGE_A = [&](int t){
    short* base = S + (t & 1) * 12288;
    gl_lds16(aU0 + t*32, base + (w*32)*32);
    gl_lds16(aU1 + t*32, base + (w*32 + 16)*32);
  };
  auto STAGE_B = [&](int t){
    short* base = S + (t & 1) * 12288;
    gl_lds16(bU + t*32, base + 8192 + (w*16)*32);
  };
  STAGE_A(0); STAGE_B(0);
  if (NT > 1) STAGE_A(1);
  asm volatile("s_waitcnt vmcnt(2)" ::: "memory");   // tile 0's 3 loads done
  __builtin_amdgcn_s_barrier();
  for (int t = 0; t < NT; ++t){
    const short* Ab = S + (t & 1) * 12288;
    const short* Bb = Ab + 8192;
    bf16x8 bfr[4];
    #pragma unroll
    for (int nf = 0; nf < 4; ++nf)
      bfr[nf] = *(const bf16x8*)(Bb + (wc*64 + nf*16 + mr)*32 + sw);
    #pragma unroll
    for (int ph = 0; ph < 4; ++ph){
      bf16x8 af = *(const bf16x8*)(Ab + (wr*64 + ph*16 + mr)*32 + sw);
      if (ph == 1 && t+1 < NT) STAGE_B(t+1);       // B of t+1 -> buf (t+1)&1
      #pragma unroll
      for (int nf = 0; nf < 4; ++nf)
        acc[ph][nf] = __builtin_amdgcn_mfma_f32_16x16x32_bf16(af, bfr[nf], acc[ph][nf],0,0,0);
    }
    __builtin_amdgcn_s_barrier();            // all waves done reading buf t&1
    if (t+2 < NT){
      STAGE_A(t+2);                          // A of t+2 -> just-freed buf
      asm volatile("s_waitcnt vmcnt(2)" ::: "memory");   // A(t+1)+B(t+1) landed
    } else if (t+1 < NT){
      asm volatile("s_waitcnt vmcnt(0)" ::: "memory");   // tail drain (once)
    }
    __builtin_amdgcn_s_barrier();            // all waves' t+1 loads visible
  }
}

// ---------- prep: plain f32->bf16 converts (in_proj, post x4, x_proj_w, dt_proj_w) ----------
__global__ __launch_bounds__(256) void k_conv_all(
    const float* __restrict__ in_proj,
    const float* __restrict__ pw0, const float* __restrict__ pw1,
    const float* __restrict__ pw2, const float* __restrict__ pw3,
    const float* __restrict__ xpw, const float* __restrict__ dtw,
    short* __restrict__ inp_bf, short* __restrict__ postw_bf,
    short* __restrict__ xpw_bf, short* __restrict__ dtw_bf)
{
  int q = blockIdx.x*256 + threadIdx.x;   // quad index, total 332800
  const float* src; short* dst; int off;
  if (q < 65536){ src = in_proj; dst = inp_bf; off = q; }
  else if (q < 65536 + 262144){
    int r = q - 65536; int g = r >> 16; int loc = r & 65535;
    src = (g==0)?pw0:(g==1)?pw1:(g==2)?pw2:pw3;
    dst = postw_bf + g*262144; off = loc;
  }
  else if (q < 65536 + 262144 + 3072){ src = xpw; dst = xpw_bf; off = q - (65536+262144); }
  else { src = dtw; dst = dtw_bf; off = q - (65536+262144+3072); }
  float4 v = *(const float4*)(src + off*4);
  uint32_t p0 = (uint32_t)(uint16_t)f2bf(v.x) | ((uint32_t)(uint16_t)f2bf(v.y) << 16);
  uint32_t p1 = (uint32_t)(uint16_t)f2bf(v.z) | ((uint32_t)(uint16_t)f2bf(v.w) << 16);
  uint2 p; p.x = p0; p.y = p1;
  *(uint2*)(dst + off*4) = p;
}

// ---------- prep: LDS-tiled transpose+convert (pre_w x4 -> wpreT, out_proj -> woutT) ----------
__global__ __launch_bounds__(256) void k_transp(
    const float* __restrict__ pw0, const float* __restrict__ pw1,
    const float* __restrict__ pw2, const float* __restrict__ pw3,
    const float* __restrict__ outp,
    short* __restrict__ wpreT, short* __restrict__ woutT)
{
  __shared__ float tile[64][65];
  int which = blockIdx.y;
  const float* src = (which==0)?pw0:(which==1)?pw1:(which==2)?pw2:(which==3)?pw3:outp;
  short* dst = (which < 4) ? (wpreT + which*262144) : woutT;
  int bi = blockIdx.x >> 3, bj = blockIdx.x & 7;
  int r0 = bi*64, c0 = bj*64;
  int t = threadIdx.x;
  int row = t >> 2, cg = t & 3;
  const float4* s4 = (const float4*)(src + (r0+row)*512 + c0 + cg*16);
  #pragma unroll
  for (int i=0;i<4;i++){
    float4 v = s4[i];
    tile[row][cg*16 + i*4 + 0] = v.x;
    tile[row][cg*16 + i*4 + 1] = v.y;
    tile[row][cg*16 + i*4 + 2] = v.z;
    tile[row][cg*16 + i*4 + 3] = v.w;
  }
  __syncthreads();
  int oc = t >> 2;
  short tmp[16];
  #pragma unroll
  for (int i=0;i<16;i++) tmp[i] = f2bf(tile[cg*16 + i][oc]);
  short* dp = dst + (size_t)(c0+oc)*512 + r0 + cg*16;
  *(bf16x8*)(dp)     = *(bf16x8*)tmp;
  *(bf16x8*)(dp + 8) = *((bf16x8*)tmp + 1);
}

__global__ __launch_bounds__(256) void k_tok(const float* __restrict__ t, short* __restrict__ o){
  int i = (blockIdx.x*256 + threadIdx.x) * 4;
  float4 v = *(const float4*)(t + i);
  uint32_t p0 = (uint32_t)(uint16_t)f2bf(v.x) | ((uint32_t)(uint16_t)f2bf(v.y) << 16);
  uint32_t p1 = (uint32_t)(uint16_t)f2bf(v.z) | ((uint32_t)(uint16_t)f2bf(v.w) << 16);
  uint2 p; p.x = p0; p.y = p1;
  *(uint2*)(o + i) = p;
}

// ---------- prep: b_xz (blocks 0-7) + gains/biasc (block 8) ----------
__global__ __launch_bounds__(256) void k_bxz_gains(const float* __restrict__ in_proj,
    const float* __restrict__ b0, const float* __restrict__ b1,
    const float* __restrict__ b2, const float* __restrict__ b3,
    const float* __restrict__ gl,
    const float* __restrict__ pb0, const float* __restrict__ pb1,
    const float* __restrict__ pb2, const float* __restrict__ pb3,
    float* __restrict__ bxz, float* __restrict__ gains, float* __restrict__ biasc)
{
  if (blockIdx.x < 8){
    int idx = blockIdx.x*256 + threadIdx.x;   // 0..2047
    int g = idx >> 9, i = idx & 511;
    const float* bb = (g==0)?b0:(g==1)?b1:(g==2)?b2:b3;
    float s = 0.f;
    for (int t=0;t<512;t++) s += in_proj[i*512+t]*bb[t];
    bxz[idx] = s;
  } else {
    float m = fmaxf(fmaxf(gl[0], gl[1]), fmaxf(gl[2], gl[3]));
    float e0 = expf(gl[0]-m), e1 = expf(gl[1]-m), e2 = expf(gl[2]-m), e3 = expf(gl[3]-m);
    float s = e0+e1+e2+e3;
    float g0 = e0/s, g1 = e1/s, g2 = e2/s, g3 = e3/s;
    int t = threadIdx.x;
    if (t == 0){ gains[0]=g0; gains[1]=g1; gains[2]=g2; gains[3]=g3; }
    biasc[t]     = g0*pb0[t]     + g1*pb1[t]     + g2*pb2[t]     + g3*pb3[t];
    biasc[t+256] = g0*pb0[t+256] + g1*pb1[t+256] + g2*pb2[t+256] + g3*pb3[t+256];
  }
}

// ---------- register-GEMM core for the tiny weight-fuse GEMMs ----------
__device__ __forceinline__ void mfma_2x4_k(const short* a0, const short* a1,
    const short* b0, const short* b1, const short* b2, const short* b3,
    int K, f32x4 acc[2][4])
{
  for (int k0 = 0; k0 < K; k0 += 32){
    bf16x8 av0 = *(const bf16x8*)(a0 + k0);
    bf16x8 av1 = *(const bf16x8*)(a1 + k0);
    bf16x8 bv0 = *(const bf16x8*)(b0 + k0);
    bf16x8 bv1 = *(const bf16x8*)(b1 + k0);
    bf16x8 bv2 = *(const bf16x8*)(b2 + k0);
    bf16x8 bv3 = *(const bf16x8*)(b3 + k0);
    acc[0][0] = __builtin_amdgcn_mfma_f32_16x16x32_bf16(av0, bv0, acc[0][0],0,0,0);
    acc[0][1] = __builtin_amdgcn_mfma_f32_16x16x32_bf16(av0, bv1, acc[0][1],0,0,0);
    acc[0][2] = __builtin_amdgcn_mfma_f32_16x16x32_bf16(av0, bv2, acc[0][2],0,0,0);
    acc[0][3] = __builtin_amdgcn_mfma_f32_16x16x32_bf16(av0, bv3, acc[0][3],0,0,0);
    acc[1][0] = __builtin_amdgcn_mfma_f32_16x16x32_bf16(av1, bv0, acc[1][0],0,0,0);
    acc[1][1] = __builtin_amdgcn_mfma_f32_16x16x32_bf16(av1, bv1, acc[1][1],0,0,0);
    acc[1][2] = __builtin_amdgcn_mfma_f32_16x16x32_bf16(av1, bv2, acc[1][2],0,0,0);
    acc[1][3] = __builtin_amdgcn_mfma_f32_16x16x32_bf16(av1, bv3, acc[1][3],0,0,0);
  }
}

// ---------- merged weight-fuse: z<4 -> W_xz[g]; z>=4 -> Wog[g] ----------
__global__ __launch_bounds__(256) void k_wfuse(const short* __restrict__ inp_bf,
    const short* __restrict__ wpreT, const short* __restrict__ postw_bf,
    const short* __restrict__ woutT, const float* __restrict__ gains,
    short* __restrict__ wxz, short* __restrict__ wogc)
{
  int z = blockIdx.z; int g = z & 3, which = z >> 2;
  int bn = blockIdx.x * 64, bm = blockIdx.y * 128;
  int lane = threadIdx.x & 63, wave = threadIdx.x >> 6;
  int mr = lane & 15, qk = (lane >> 4) * 8, quad = lane >> 4;
  const short* Am = which ? (postw_bf + g*262144) : inp_bf;
  const short* Bm = which ? woutT : (wpreT + g*262144);
  const short* a0 = Am + (bm + wave*32 + mr)*512 + qk;
  const short* a1 = a0 + 16*512;
  const short* b0 = Bm + (bn +  0 + mr)*512 + qk;
  const short* b1 = Bm + (bn + 16 + mr)*512 + qk;
  const short* b2 = Bm + (bn + 32 + mr)*512 + qk;
  const short* b3 = Bm + (bn + 48 + mr)*512 + qk;
  f32x4 acc[2][4] = {};
  mfma_2x4_k(a0, a1, b0, b1, b2, b3, 512, acc);
  float gain = which ? gains[g] : 1.f;
  #pragma unroll
  for (int s=0;s<2;s++)
    #pragma unroll
    for (int t=0;t<4;t++)
      #pragma unroll
      for (int r=0;r<4;r++){
        int row = bm + wave*32 + s*16 + quad*4 + r;
        int col = bn + t*16 + mr;
        if (which) wogc[row*2048 + g*512 + col] = f2bf(gain * acc[s][t][r]);
        else       wxz[g*262144 + row*512 + col] = f2bf(acc[s][t][r]);
      }
}

// ---------- GEMM1+conv fused (r11-verified): BM=245, BN=128, BK=32, K=512 ----------
__global__ __launch_bounds__(512) void k_gemm1c(const short* __restrict__ tok,
    const short* __restrict__ wxz, const float* __restrict__ bxz,
    const float* __restrict__ cxw, const float* __restrict__ cxb,
    const float* __restrict__ czw, const float* __restrict__ czb,
    short* __restrict__ ycat)
{
  __shared__ __align__(16) short S[24576];    // 48 KB staging; reused as conv tile [256][72]
  int bid = blockIdx.x;                       // 1648 = 8 * 206, bijective XCD swizzle
  int swz = (bid & 7) * 206 + (bid >> 3);
  int g = swz / 412, rem = swz - g*412;
  int blk = rem >> 2, bn = (rem & 3) * 128;
  int bm = blk * 245;                         // multiple of 49 -> b-group aligned
  int nreal = min(245, 25088 - bm);           // last block has 98 real rows
  int tid = threadIdx.x, lane = tid & 63, w = tid >> 6;

  int rl = lane >> 2;                                 // row within 16-row unit
  int gch = ((lane & 3) ^ ((lane >> 3) & 3)) * 8;     // pre-swizzled global chunk
  const short* aU[2];
  #pragma unroll
  for (int j = 0; j < 2; ++j){
    int p = w*32 + j*16 + rl;
    int pr = (p < nreal) ? p : (nreal - 1);           // clamp padded rows
    int q49 = pr / 49;
    int l49 = pr - q49*49;
    int b = blk*5 + q49;
    int sl = perm_idx(g, l49);
    aU[j] = tok + ((size_t)(b*49 + sl))*512 + gch;
  }
  const short* bU = wxz + (size_t)g*262144 + (size_t)(bn + w*16 + rl)*512 + gch;

  f32x4 acc[4][4] = {};
  kcore256x128<16>(aU[0], aU[1], bU, S, w, lane, acc);

  // ---- fused epilogue: two 64-col halves; tile [256][72] (144B rows, aligned) ----
  int wr = w >> 1, wc = w & 1, mr = lane & 15, quad = lane >> 4;
  int rowgrp = tid >> 3, oct = tid & 7;      // 64 row-groups x 8 col-octs
  #pragma unroll
  for (int h = 0; h < 2; ++h){
    if (wc == h){
      #pragma unroll
      for (int mf = 0; mf < 4; ++mf)
        #pragma unroll
        for (int nf = 0; nf < 4; ++nf)
          #pragma unroll
          for (int rr = 0; rr < 4; ++rr){
            int row = wr*64 + mf*16 + quad*4 + rr;
            int col = nf*16 + mr;
            S[row*72 + col] = f2bf(acc[mf][nf][rr] + bxz[g*512 + bn + h*64 + col]);
          }
    }
    __syncthreads();                         // tile half h visible
    int colbase = bn + h*64 + oct*8;         // global xz column (== ycat channel)
    bool isx = colbase < 256;
    const float* wsrc = isx ? cxw : czw;
    const float* bsrc = isx ? cxb : czb;
    int cc0 = isx ? colbase : colbase - 256;
    float w0[8], w1[8], w2[8], cb[8];
    #pragma unroll
    for (int e = 0; e < 8; ++e){
      w0[e] = wsrc[(cc0+e)*3]; w1[e] = wsrc[(cc0+e)*3+1]; w2[e] = wsrc[(cc0+e)*3+2];
      cb[e] = bsrc[cc0+e];
    }
    for (int i = 0; i < 4; ++i){
      int p = rowgrp + 64*i;
      if (p < nreal){
        int l = p - (p/49)*49;
        bf16x8 vm = {}, vp = {};
        bf16x8 v0 = *(const bf16x8*)(S + p*72 + oct*8);
        if (l > 0)  vm = *(const bf16x8*)(S + (p-1)*72 + oct*8);
        if (l < 48) vp = *(const bf16x8*)(S + (p+1)*72 + oct*8);
        short ov[8];
        #pragma unroll
        for (int e = 0; e < 8; ++e){
          float x = w0[e]*bf2f(vm[e]) + w1[e]*bf2f(v0[e]) + w2[e]*bf2f(vp[e]) + cb[e];
          ov[e] = f2bf(x / (1.f + __expf(-x)));
        }
        *(bf16x8*)(ycat + (size_t)(bm + p)*2048 + g*512 + colbase) = *(bf16x8*)ov;
      }
    }
    __syncthreads();                         // conv reads done before half 1 overwrites
  }
}

// ---------- k_xps: FUSED x_proj GEMM + LN + dt GEMM + softplus + selective scan ----------
// One block (256 thr, 4 waves) per (g,b). All intermediates in LDS; dtln/bc
// global buffers eliminated. Rounding path bit-identical to the split kernels:
// u read as bf16, dt rounded to bf16 before scan, B/C kept f32.
// LDS (58,016 B): Us[49][264] bf16 (25,872; 528B rows: 16B-aligned, 2-way-free)
//   | xln[49][40] bf16 (3,920) | bcs[49][16] f32 (3,136)
//   | R: xd[49][52] f32 (10,192) overlaid later by ddt[49][256] bf16 (25,088).
__global__ __launch_bounds__(256) void k_xps(short* __restrict__ ycat,
    const short* __restrict__ xpw_bf, const float* __restrict__ lnw, const float* __restrict__ lnb,
    const short* __restrict__ dtw_bf, const float* __restrict__ dtb,
    const float* __restrict__ Alog, const float* __restrict__ Dp)
{
  __shared__ __align__(16) char smem[58016];
  short* Us  = (short*)smem;                    // [49][264]
  short* xln = (short*)(smem + 25872);          // [49][40]
  float* bcs = (float*)(smem + 29792);          // [49][16]
  float* xd  = (float*)(smem + 32928);          // [49][52]  (phase 1-2)
  short* ddt = (short*)(smem + 32928);          // [49][256] (phase 3+, xd dead)

  int bid = blockIdx.x;                         // 2048 = 8 * 256, bijective XCD swizzle
  int swz = (bid & 7) * 256 + (bid >> 3);
  int g = swz >> 9, b = swz & 511;
  int tid = threadIdx.x, lane = tid & 63, w = tid >> 6;
  int mr = lane & 15, quad = lane >> 4, qk = quad * 8;

  // ---- stage u[49][256] -> Us (padded rows) ----
  const short* ubase = ycat + (size_t)(b*49)*2048 + g*512;
  for (int idx = tid; idx < 1568; idx += 256){
    int l = idx >> 5, cc = (idx & 31) * 8;
    *(bf16x8*)(Us + l*264 + cc) = *(const bf16x8*)(ubase + (size_t)l*2048 + cc);
  }
  __syncthreads();

  // ---- phase 1: x_dbl = u @ xpw^T  (M=49 pad 64, N=48, K=256) ----
  {
    int ar = w*16 + mr; if (ar > 48) ar = 48;        // clamp: rows >48 discarded
    const short* ap = Us + ar*264 + qk;
    f32x4 acc[3] = {};
    #pragma unroll
    for (int k0 = 0; k0 < 256; k0 += 32){
      bf16x8 av = *(const bf16x8*)(ap + k0);
      #pragma unroll
      for (int t = 0; t < 3; ++t){
        bf16x8 bv = *(const bf16x8*)(xpw_bf + (t*16 + mr)*256 + qk + k0);
        acc[t] = __builtin_amdgcn_mfma_f32_16x16x32_bf16(av, bv, acc[t],0,0,0);
      }
    }
    #pragma unroll
    for (int t = 0; t < 3; ++t)
      #pragma unroll
      for (int r = 0; r < 4; ++r){
        int row = w*16 + quad*4 + r;
        if (row < 49) xd[row*52 + t*16 + mr] = acc[t][r];
      }
  }
  __syncthreads();

  // ---- phase 2: LN per row (threads 0..48) -> xln bf16 + bcs f32 ----
  if (tid < 49){
    f32x4* xr4 = (f32x4*)(xd + tid*52);
    f32x4 s = xr4[0];
    #pragma unroll
    for (int i=1;i<12;i++) s += xr4[i];
    float m = (s[0]+s[1]+s[2]+s[3]) * (1.f/48.f);
    f32x4 vs = {};
    #pragma unroll
    for (int i=0;i<12;i++){ f32x4 d = xr4[i] - m; vs += d*d; }
    float var = (vs[0]+vs[1]+vs[2]+vs[3]) * (1.f/48.f);
    float rstd = rsqrtf(var + 1e-5f);
    const f32x4* g4 = (const f32x4*)lnw;
    const f32x4* b4 = (const f32x4*)lnb;
    uint32_t* xlr = (uint32_t*)(xln + tid*40);
    #pragma unroll
    for (int i=0;i<8;i++){       // cols 0..31 -> xln bf16
      f32x4 v = (xr4[i] - m) * rstd * g4[i] + b4[i];
      xlr[2*i]   = (uint32_t)(uint16_t)f2bf(v[0]) | ((uint32_t)(uint16_t)f2bf(v[1]) << 16);
      xlr[2*i+1] = (uint32_t)(uint16_t)f2bf(v[2]) | ((uint32_t)(uint16_t)f2bf(v[3]) << 16);
    }
    f32x4* bco = (f32x4*)(bcs + tid*16);
    #pragma unroll
    for (int i=8;i<12;i++)       // cols 32..47 -> bcs f32
      bco[i-8] = (xr4[i] - m) * rstd * g4[i] + b4[i];
  }
  __syncthreads();               // xd dead from here; ddt may overwrite R

  // ---- phase 3: dt = xln[:,0:32] @ dtw^T (K=32, N=256) + bias + softplus -> ddt ----
  {
    int ar = w*16 + mr; if (ar > 48) ar = 48;
    bf16x8 a = *(const bf16x8*)(xln + ar*40 + qk);
    #pragma unroll 4
    for (int nt=0; nt<16; nt++){
      int col = nt*16 + mr;
      bf16x8 bv = *(const bf16x8*)(dtw_bf + col*32 + qk);
      float dtbv = dtb[col];
      f32x4 acc = {};
      acc = __builtin_amdgcn_mfma_f32_16x16x32_bf16(a, bv, acc,0,0,0);
      #pragma unroll
      for (int r=0;r<4;r++){
        int row = w*16 + quad*4 + r;
        if (row < 49){
          float dtv = acc[r] + dtbv;
          float e  = __expf(dtv);
          float sp = __logf(1.f + e);
          float delta = (dtv > 15.f) ? dtv : sp;
          ddt[row*256 + col] = f2bf(delta);
        }
      }
    }
  }
  __syncthreads();

  // ---- phase 4: selective scan (thread = channel d), y -> ycat in place ----
  {
    int d = tid;
    float A[8], h[8];
    f32x4 a0 = *(const f32x4*)(Alog + d*8);
    f32x4 a1 = *(const f32x4*)(Alog + d*8 + 4);
    #pragma unroll
    for (int n=0;n<4;n++){ A[n] = -__expf(a0[n]); A[n+4] = -__expf(a1[n]); h[n]=0.f; h[n+4]=0.f; }
    float Dpar = Dp[d];
    short* uptr = ycat + (size_t)(b*49)*2048 + g*512 + d;

    for (int l=0;l<49;l++){
      float delta = bf2f(ddt[l*256 + d]);
      float u     = bf2f(Us[l*264 + d]);
      const f32x4* bcr = (const f32x4*)(bcs + l*16);
      f32x4 B0 = bcr[0], B1 = bcr[1], C0 = bcr[2], C1 = bcr[3];
      float du = delta * u;
      float y = 0.f;
      #pragma unroll
      for (int n=0;n<4;n++){
        h[n] = h[n]*__expf(delta*A[n]) + du*B0[n];
        y += h[n]*C0[n];
      }
      #pragma unroll
      for (int n=0;n<4;n++){
        h[n+4] = h[n+4]*__expf(delta*A[n+4]) + du*B1[n];
        y += h[n+4]*C1[n];
      }
      uptr[l*2048] = f2bf(y + Dpar*u);
    }
  }
}

// ---------- final GEMM: 256x128 tile, BK=32, K=2048 (NT=64), grid 392, XCD-swz ----------
__global__ __launch_bounds__(512) void k_gemmF(const short* __restrict__ ycat,
    const short* __restrict__ wogc, const float* __restrict__ biasc,
    float* __restrict__ out)
{
  __shared__ __align__(16) short S[24576];    // 48 KB: 2 buf x (A 16KB | B 8KB)
  int bid = blockIdx.x;                       // 392 = 8 * 49, bijective XCD swizzle
  int swz = (bid & 7) * 49 + (bid >> 3);
  int bm = (swz >> 2) * 256, bn = (swz & 3) * 128;
  int tid = threadIdx.x, lane = tid & 63, w = tid >> 6;

  int rl = lane >> 2;                                 // row within 16-row unit
  int gch = ((lane & 3) ^ ((lane >> 3) & 3)) * 8;     // pre-swizzled global chunk
  const short* aU0 = ycat + (size_t)(bm + w*32      + rl)*2048 + gch;
  const short* aU1 = ycat + (size_t)(bm + w*32 + 16 + rl)*2048 + gch;
  const short* bU  = wogc + (size_t)(bn + w*16      + rl)*2048 + gch;

  f32x4 acc[4][4] = {};
  kcore256x128<64>(aU0, aU1, bU, S, w, lane, acc);

  int wr = w >> 1, wc = w & 1, mr = lane & 15, quad = lane >> 4;
  #pragma unroll
  for (int mf = 0; mf < 4; ++mf)
    #pragma unroll
    for (int rr = 0; rr < 4; ++rr){
      int row = bm + wr*64 + mf*16 + quad*4 + rr;
      float* orow = out + (size_t)row*512;
      #pragma unroll
      for (int nf = 0; nf < 4; ++nf){
        int col = bn + wc*64 + nf*16 + mr;
        orow[col] = acc[mf][nf][rr] + biasc[col];
      }
    }
}

// ---------- launch ----------
extern "C" void kernel_launch(void* const* d_in, const int* in_sizes, int n_in,
                              void* d_out, int out_size, void* d_ws, size_t ws_size,
                              hipStream_t stream)
{
  const float* tokens    = (const float*)d_in[0];
  const float* pre_w[4]  = {(const float*)d_in[1], (const float*)d_in[3], (const float*)d_in[5], (const float*)d_in[7]};
  const float* pre_b[4]  = {(const float*)d_in[2], (const float*)d_in[4], (const float*)d_in[6], (const float*)d_in[8]};
  const float* post_w[4] = {(const float*)d_in[9], (const float*)d_in[11], (const float*)d_in[13], (const float*)d_in[15]};
  const float* post_b[4] = {(const float*)d_in[10], (const float*)d_in[12], (const float*)d_in[14], (const float*)d_in[16]};
  const float* in_proj   = (const float*)d_in[17];
  const float* conv_x_w  = (const float*)d_in[18];
  const float* conv_x_b  = (const float*)d_in[19];
  const float* conv_z_w  = (const float*)d_in[20];
  const float* conv_z_b  = (const float*)d_in[21];
  const float* x_proj_w  = (const float*)d_in[22];
  const float* ln_w      = (const float*)d_in[23];
  const float* ln_b      = (const float*)d_in[24];
  const float* dt_proj_w = (const float*)d_in[25];
  const float* dt_proj_b = (const float*)d_in[26];
  const float* A_log     = (const float*)d_in[27];
  const float* D_param   = (const float*)d_in[28];
  const float* out_proj  = (const float*)d_in[29];
  const float* gate_log  = (const float*)d_in[30];

  char* ws = (char*)d_ws;
  size_t o = 0;
  short* tok_bf   = (short*)(ws + o); o += 25690112;   // 12845056 bf16
  short* wpreT    = (short*)(ws + o); o += 2097152;    // 4x 512x512 bf16 (transposed)
  short* inp_bf   = (short*)(ws + o); o += 524288;
  short* postw_bf = (short*)(ws + o); o += 2097152;
  short* woutT    = (short*)(ws + o); o += 524288;
  short* wogc     = (short*)(ws + o); o += 2097152;    // 512 x 2048 bf16
  short* wxz      = (short*)(ws + o); o += 2097152;    // 4x 512x512 bf16
  short* xpw_bf   = (short*)(ws + o); o += 24576;      // 48x256 bf16
  short* dtw_bf   = (short*)(ws + o); o += 16384;      // 256x32 bf16
  float* bxz      = (float*)(ws + o); o += 8192;
  float* gains    = (float*)(ws + o); o += 64;
  float* biasc    = (float*)(ws + o); o += 2048;
  size_t scratch_off = o;
  o += 102760448;                                      // (unused now; kept for layout stability)
  short* ycat     = (short*)(ws + o); o += 102760448;  // 25088 x 2048 bf16
  (void)scratch_off;

  k_conv_all<<<1300, 256, 0, stream>>>(in_proj,
      post_w[0], post_w[1], post_w[2], post_w[3],
      x_proj_w, dt_proj_w, inp_bf, postw_bf, xpw_bf, dtw_bf);
  k_transp<<<dim3(64,5), 256, 0, stream>>>(pre_w[0], pre_w[1], pre_w[2], pre_w[3],
      out_proj, wpreT, woutT);
  k_tok<<<12544, 256, 0, stream>>>(tokens, tok_bf);
  k_bxz_gains<<<9, 256, 0, stream>>>(in_proj, pre_b[0], pre_b[1], pre_b[2], pre_b[3],
      gate_log, post_b[0], post_b[1], post_b[2], post_b[3], bxz, gains, biasc);
  k_wfuse<<<dim3(8,4,8), 256, 0, stream>>>(inp_bf, wpreT, postw_bf, woutT, gains, wxz, wogc);
  k_gemm1c<<<dim3(1648), 512, 0, stream>>>(tok_bf, wxz, bxz,
      conv_x_w, conv_x_b, conv_z_w, conv_z_b, ycat);
  k_xps<<<dim3(2048), 256, 0, stream>>>(ycat, xpw_bf, ln_w, ln_b,
      dtw_bf, dt_proj_b, A_log, D_param);
  k_gemmF<<<dim3(392), 512, 0, stream>>>(ycat, wogc, biasc, (float*)d_out);
}

// Round 13
// 445.289 us; speedup vs baseline: 1.0321x; 1.0321x over previous
//
#include <hip/hip_runtime.h>
#include <stdint.h>

// ---------- types ----------
typedef __attribute__((ext_vector_type(8))) short bf16x8;   // 8 bf16 in 4 VGPRs
typedef __attribute__((ext_vector_type(4))) float f32x4;

__device__ __forceinline__ float bf2f(short u){
  union { float f; uint32_t i; } v; v.i = ((uint32_t)(uint16_t)u) << 16; return v.f;
}
__device__ __forceinline__ short f2bf(float x){
  union { float f; uint32_t i; } v; v.f = x;
  uint32_t r = v.i + 0x7FFFu + ((v.i >> 16) & 1u);   // RNE
  return (short)(r >> 16);
}

// async global->LDS, 16B per lane; LDS dest = wave-uniform base + lane*16
__device__ __forceinline__ void gl_lds16(const short* g, short* l){
  __builtin_amdgcn_global_load_lds(
      (__attribute__((address_space(1))) void*)(short*)g,
      (__attribute__((address_space(3))) void*)l, 16, 0, 0);
}

// ---------- permutation tables (WIN=7, compile-time) ----------
__device__ const int d_DIAG[49] = {0,1,7,2,8,14,3,9,15,21,4,10,16,22,28,5,11,17,23,29,35,
  6,12,18,24,30,36,42,13,19,25,31,37,43,20,26,32,38,44,27,33,39,45,34,40,46,41,47,48};
__device__ const int d_ANTI[49] = {6,5,13,4,12,20,3,11,19,27,2,10,18,26,34,1,9,17,25,33,41,
  0,8,16,24,32,40,48,7,15,23,31,39,47,14,22,30,38,46,21,29,37,45,28,36,44,35,43,42};

__device__ __forceinline__ int perm_idx(int g, int l){
  if (g == 0) return l;
  if (g == 1) return (l % 7) * 7 + l / 7;  // V_IDX
  if (g == 2) return d_DIAG[l];
  return d_ANTI[l];
}

// ---------- 256x128 K-loop core: BK=32, 8 waves (4M x 2N), 48KB LDS ----------
// (proven r6/r11) LDS buffer stride 12288 shorts: A [256r][32] at +0, B [128r][32]
// at +8192. Counted vmcnt(2), 2 barriers/tile. Chunk XOR-swizzle both-sides.
template<int NT>
__device__ __forceinline__ void kcore256x128(
    const short* aU0, const short* aU1, const short* bU,
    short* S, int w, int lane, f32x4 acc[4][4])
{
  int wr = w >> 1, wc = w & 1;
  int mr = lane & 15, quad = lane >> 4;
  int sw = (quad ^ ((mr >> 1) & 3)) * 8;     // swizzled chunk offset (shorts)
  auto STAGE_A = [&](int t){
    short* base = S + (t & 1) * 12288;
    gl_lds16(aU0 + t*32, base + (w*32)*32);
    gl_lds16(aU1 + t*32, base + (w*32 + 16)*32);
  };
  auto STAGE_B = [&](int t){
    short* base = S + (t & 1) * 12288;
    gl_lds16(bU + t*32, base + 8192 + (w*16)*32);
  };
  STAGE_A(0); STAGE_B(0);
  if (NT > 1) STAGE_A(1);
  asm volatile("s_waitcnt vmcnt(2)" ::: "memory");   // tile 0's 3 loads done
  __builtin_amdgcn_s_barrier();
  for (int t = 0; t < NT; ++t){
    const short* Ab = S + (t & 1) * 12288;
    const short* Bb = Ab + 8192;
    bf16x8 bfr[4];
    #pragma unroll
    for (int nf = 0; nf < 4; ++nf)
      bfr[nf] = *(const bf16x8*)(Bb + (wc*64 + nf*16 + mr)*32 + sw);
    #pragma unroll
    for (int ph = 0; ph < 4; ++ph){
      bf16x8 af = *(const bf16x8*)(Ab + (wr*64 + ph*16 + mr)*32 + sw);
      if (ph == 1 && t+1 < NT) STAGE_B(t+1);       // B of t+1 -> buf (t+1)&1
      #pragma unroll
      for (int nf = 0; nf < 4; ++nf)
        acc[ph][nf] = __builtin_amdgcn_mfma_f32_16x16x32_bf16(af, bfr[nf], acc[ph][nf],0,0,0);
    }
    __builtin_amdgcn_s_barrier();            // all waves done reading buf t&1
    if (t+2 < NT){
      STAGE_A(t+2);                          // A of t+2 -> just-freed buf
      asm volatile("s_waitcnt vmcnt(2)" ::: "memory");   // A(t+1)+B(t+1) landed
    } else if (t+1 < NT){
      asm volatile("s_waitcnt vmcnt(0)" ::: "memory");   // tail drain (once)
    }
    __builtin_amdgcn_s_barrier();            // all waves' t+1 loads visible
  }
}

// ---------- prep: plain f32->bf16 converts (in_proj, post x4, x_proj_w, dt_proj_w) ----------
__global__ __launch_bounds__(256) void k_conv_all(
    const float* __restrict__ in_proj,
    const float* __restrict__ pw0, const float* __restrict__ pw1,
    const float* __restrict__ pw2, const float* __restrict__ pw3,
    const float* __restrict__ xpw, const float* __restrict__ dtw,
    short* __restrict__ inp_bf, short* __restrict__ postw_bf,
    short* __restrict__ xpw_bf, short* __restrict__ dtw_bf)
{
  int q = blockIdx.x*256 + threadIdx.x;   // quad index, total 332800
  const float* src; short* dst; int off;
  if (q < 65536){ src = in_proj; dst = inp_bf; off = q; }
  else if (q < 65536 + 262144){
    int r = q - 65536; int g = r >> 16; int loc = r & 65535;
    src = (g==0)?pw0:(g==1)?pw1:(g==2)?pw2:pw3;
    dst = postw_bf + g*262144; off = loc;
  }
  else if (q < 65536 + 262144 + 3072){ src = xpw; dst = xpw_bf; off = q - (65536+262144); }
  else { src = dtw; dst = dtw_bf; off = q - (65536+262144+3072); }
  float4 v = *(const float4*)(src + off*4);
  uint32_t p0 = (uint32_t)(uint16_t)f2bf(v.x) | ((uint32_t)(uint16_t)f2bf(v.y) << 16);
  uint32_t p1 = (uint32_t)(uint16_t)f2bf(v.z) | ((uint32_t)(uint16_t)f2bf(v.w) << 16);
  uint2 p; p.x = p0; p.y = p1;
  *(uint2*)(dst + off*4) = p;
}

// ---------- prep: LDS-tiled transpose+convert (pre_w x4 -> wpreT, out_proj -> woutT) ----------
__global__ __launch_bounds__(256) void k_transp(
    const float* __restrict__ pw0, const float* __restrict__ pw1,
    const float* __restrict__ pw2, const float* __restrict__ pw3,
    const float* __restrict__ outp,
    short* __restrict__ wpreT, short* __restrict__ woutT)
{
  __shared__ float tile[64][65];
  int which = blockIdx.y;
  const float* src = (which==0)?pw0:(which==1)?pw1:(which==2)?pw2:(which==3)?pw3:outp;
  short* dst = (which < 4) ? (wpreT + which*262144) : woutT;
  int bi = blockIdx.x >> 3, bj = blockIdx.x & 7;
  int r0 = bi*64, c0 = bj*64;
  int t = threadIdx.x;
  int row = t >> 2, cg = t & 3;
  const float4* s4 = (const float4*)(src + (r0+row)*512 + c0 + cg*16);
  #pragma unroll
  for (int i=0;i<4;i++){
    float4 v = s4[i];
    tile[row][cg*16 + i*4 + 0] = v.x;
    tile[row][cg*16 + i*4 + 1] = v.y;
    tile[row][cg*16 + i*4 + 2] = v.z;
    tile[row][cg*16 + i*4 + 3] = v.w;
  }
  __syncthreads();
  int oc = t >> 2;
  short tmp[16];
  #pragma unroll
  for (int i=0;i<16;i++) tmp[i] = f2bf(tile[cg*16 + i][oc]);
  short* dp = dst + (size_t)(c0+oc)*512 + r0 + cg*16;
  *(bf16x8*)(dp)     = *(bf16x8*)tmp;
  *(bf16x8*)(dp + 8) = *((bf16x8*)tmp + 1);
}

__global__ __launch_bounds__(256) void k_tok(const float* __restrict__ t, short* __restrict__ o){
  int i = (blockIdx.x*256 + threadIdx.x) * 4;
  float4 v = *(const float4*)(t + i);
  uint32_t p0 = (uint32_t)(uint16_t)f2bf(v.x) | ((uint32_t)(uint16_t)f2bf(v.y) << 16);
  uint32_t p1 = (uint32_t)(uint16_t)f2bf(v.z) | ((uint32_t)(uint16_t)f2bf(v.w) << 16);
  uint2 p; p.x = p0; p.y = p1;
  *(uint2*)(o + i) = p;
}

// ---------- prep: b_xz (blocks 0-7) + gains/biasc (block 8) ----------
__global__ __launch_bounds__(256) void k_bxz_gains(const float* __restrict__ in_proj,
    const float* __restrict__ b0, const float* __restrict__ b1,
    const float* __restrict__ b2, const float* __restrict__ b3,
    const float* __restrict__ gl,
    const float* __restrict__ pb0, const float* __restrict__ pb1,
    const float* __restrict__ pb2, const float* __restrict__ pb3,
    float* __restrict__ bxz, float* __restrict__ gains, float* __restrict__ biasc)
{
  if (blockIdx.x < 8){
    int idx = blockIdx.x*256 + threadIdx.x;   // 0..2047
    int g = idx >> 9, i = idx & 511;
    const float* bb = (g==0)?b0:(g==1)?b1:(g==2)?b2:b3;
    float s = 0.f;
    for (int t=0;t<512;t++) s += in_proj[i*512+t]*bb[t];
    bxz[idx] = s;
  } else {
    float m = fmaxf(fmaxf(gl[0], gl[1]), fmaxf(gl[2], gl[3]));
    float e0 = expf(gl[0]-m), e1 = expf(gl[1]-m), e2 = expf(gl[2]-m), e3 = expf(gl[3]-m);
    float s = e0+e1+e2+e3;
    float g0 = e0/s, g1 = e1/s, g2 = e2/s, g3 = e3/s;
    int t = threadIdx.x;
    if (t == 0){ gains[0]=g0; gains[1]=g1; gains[2]=g2; gains[3]=g3; }
    biasc[t]     = g0*pb0[t]     + g1*pb1[t]     + g2*pb2[t]     + g3*pb3[t];
    biasc[t+256] = g0*pb0[t+256] + g1*pb1[t+256] + g2*pb2[t+256] + g3*pb3[t+256];
  }
}

// ---------- register-GEMM core for the tiny weight-fuse GEMMs ----------
__device__ __forceinline__ void mfma_2x4_k(const short* a0, const short* a1,
    const short* b0, const short* b1, const short* b2, const short* b3,
    int K, f32x4 acc[2][4])
{
  for (int k0 = 0; k0 < K; k0 += 32){
    bf16x8 av0 = *(const bf16x8*)(a0 + k0);
    bf16x8 av1 = *(const bf16x8*)(a1 + k0);
    bf16x8 bv0 = *(const bf16x8*)(b0 + k0);
    bf16x8 bv1 = *(const bf16x8*)(b1 + k0);
    bf16x8 bv2 = *(const bf16x8*)(b2 + k0);
    bf16x8 bv3 = *(const bf16x8*)(b3 + k0);
    acc[0][0] = __builtin_amdgcn_mfma_f32_16x16x32_bf16(av0, bv0, acc[0][0],0,0,0);
    acc[0][1] = __builtin_amdgcn_mfma_f32_16x16x32_bf16(av0, bv1, acc[0][1],0,0,0);
    acc[0][2] = __builtin_amdgcn_mfma_f32_16x16x32_bf16(av0, bv2, acc[0][2],0,0,0);
    acc[0][3] = __builtin_amdgcn_mfma_f32_16x16x32_bf16(av0, bv3, acc[0][3],0,0,0);
    acc[1][0] = __builtin_amdgcn_mfma_f32_16x16x32_bf16(av1, bv0, acc[1][0],0,0,0);
    acc[1][1] = __builtin_amdgcn_mfma_f32_16x16x32_bf16(av1, bv1, acc[1][1],0,0,0);
    acc[1][2] = __builtin_amdgcn_mfma_f32_16x16x32_bf16(av1, bv2, acc[1][2],0,0,0);
    acc[1][3] = __builtin_amdgcn_mfma_f32_16x16x32_bf16(av1, bv3, acc[1][3],0,0,0);
  }
}

// ---------- merged weight-fuse: z<4 -> W_xz[g]; z>=4 -> Wog[g] ----------
__global__ __launch_bounds__(256) void k_wfuse(const short* __restrict__ inp_bf,
    const short* __restrict__ wpreT, const short* __restrict__ postw_bf,
    const short* __restrict__ woutT, const float* __restrict__ gains,
    short* __restrict__ wxz, short* __restrict__ wogc)
{
  int z = blockIdx.z; int g = z & 3, which = z >> 2;
  int bn = blockIdx.x * 64, bm = blockIdx.y * 128;
  int lane = threadIdx.x & 63, wave = threadIdx.x >> 6;
  int mr = lane & 15, qk = (lane >> 4) * 8, quad = lane >> 4;
  const short* Am = which ? (postw_bf + g*262144) : inp_bf;
  const short* Bm = which ? woutT : (wpreT + g*262144);
  const short* a0 = Am + (bm + wave*32 + mr)*512 + qk;
  const short* a1 = a0 + 16*512;
  const short* b0 = Bm + (bn +  0 + mr)*512 + qk;
  const short* b1 = Bm + (bn + 16 + mr)*512 + qk;
  const short* b2 = Bm + (bn + 32 + mr)*512 + qk;
  const short* b3 = Bm + (bn + 48 + mr)*512 + qk;
  f32x4 acc[2][4] = {};
  mfma_2x4_k(a0, a1, b0, b1, b2, b3, 512, acc);
  float gain = which ? gains[g] : 1.f;
  #pragma unroll
  for (int s=0;s<2;s++)
    #pragma unroll
    for (int t=0;t<4;t++)
      #pragma unroll
      for (int r=0;r<4;r++){
        int row = bm + wave*32 + s*16 + quad*4 + r;
        int col = bn + t*16 + mr;
        if (which) wogc[row*2048 + g*512 + col] = f2bf(gain * acc[s][t][r]);
        else       wxz[g*262144 + row*512 + col] = f2bf(acc[s][t][r]);
      }
}

// ---------- GEMM1+conv fused (r11-verified): BM=245, BN=128, BK=32, K=512 ----------
__global__ __launch_bounds__(512) void k_gemm1c(const short* __restrict__ tok,
    const short* __restrict__ wxz, const float* __restrict__ bxz,
    const float* __restrict__ cxw, const float* __restrict__ cxb,
    const float* __restrict__ czw, const float* __restrict__ czb,
    short* __restrict__ ycat)
{
  __shared__ __align__(16) short S[24576];    // 48 KB staging; reused as conv tile [256][72]
  int bid = blockIdx.x;                       // 1648 = 8 * 206, bijective XCD swizzle
  int swz = (bid & 7) * 206 + (bid >> 3);
  int g = swz / 412, rem = swz - g*412;
  int blk = rem >> 2, bn = (rem & 3) * 128;
  int bm = blk * 245;                         // multiple of 49 -> b-group aligned
  int nreal = min(245, 25088 - bm);           // last block has 98 real rows
  int tid = threadIdx.x, lane = tid & 63, w = tid >> 6;

  int rl = lane >> 2;                                 // row within 16-row unit
  int gch = ((lane & 3) ^ ((lane >> 3) & 3)) * 8;     // pre-swizzled global chunk
  const short* aU[2];
  #pragma unroll
  for (int j = 0; j < 2; ++j){
    int p = w*32 + j*16 + rl;
    int pr = (p < nreal) ? p : (nreal - 1);           // clamp padded rows
    int q49 = pr / 49;
    int l49 = pr - q49*49;
    int b = blk*5 + q49;
    int sl = perm_idx(g, l49);
    aU[j] = tok + ((size_t)(b*49 + sl))*512 + gch;
  }
  const short* bU = wxz + (size_t)g*262144 + (size_t)(bn + w*16 + rl)*512 + gch;

  f32x4 acc[4][4] = {};
  kcore256x128<16>(aU[0], aU[1], bU, S, w, lane, acc);

  // ---- fused epilogue: two 64-col halves; tile [256][72] (144B rows, aligned) ----
  int wr = w >> 1, wc = w & 1, mr = lane & 15, quad = lane >> 4;
  int rowgrp = tid >> 3, oct = tid & 7;      // 64 row-groups x 8 col-octs
  #pragma unroll
  for (int h = 0; h < 2; ++h){
    if (wc == h){
      #pragma unroll
      for (int mf = 0; mf < 4; ++mf)
        #pragma unroll
        for (int nf = 0; nf < 4; ++nf)
          #pragma unroll
          for (int rr = 0; rr < 4; ++rr){
            int row = wr*64 + mf*16 + quad*4 + rr;
            int col = nf*16 + mr;
            S[row*72 + col] = f2bf(acc[mf][nf][rr] + bxz[g*512 + bn + h*64 + col]);
          }
    }
    __syncthreads();                         // tile half h visible
    int colbase = bn + h*64 + oct*8;         // global xz column (== ycat channel)
    bool isx = colbase < 256;
    const float* wsrc = isx ? cxw : czw;
    const float* bsrc = isx ? cxb : czb;
    int cc0 = isx ? colbase : colbase - 256;
    float w0[8], w1[8], w2[8], cb[8];
    #pragma unroll
    for (int e = 0; e < 8; ++e){
      w0[e] = wsrc[(cc0+e)*3]; w1[e] = wsrc[(cc0+e)*3+1]; w2[e] = wsrc[(cc0+e)*3+2];
      cb[e] = bsrc[cc0+e];
    }
    for (int i = 0; i < 4; ++i){
      int p = rowgrp + 64*i;
      if (p < nreal){
        int l = p - (p/49)*49;
        bf16x8 vm = {}, vp = {};
        bf16x8 v0 = *(const bf16x8*)(S + p*72 + oct*8);
        if (l > 0)  vm = *(const bf16x8*)(S + (p-1)*72 + oct*8);
        if (l < 48) vp = *(const bf16x8*)(S + (p+1)*72 + oct*8);
        short ov[8];
        #pragma unroll
        for (int e = 0; e < 8; ++e){
          float x = w0[e]*bf2f(vm[e]) + w1[e]*bf2f(v0[e]) + w2[e]*bf2f(vp[e]) + cb[e];
          ov[e] = f2bf(x / (1.f + __expf(-x)));
        }
        *(bf16x8*)(ycat + (size_t)(bm + p)*2048 + g*512 + colbase) = *(bf16x8*)ov;
      }
    }
    __syncthreads();                         // conv reads done before half 1 overwrites
  }
}

// ---------- k_xps v2: fused x_proj + LN + dt + softplus + scan, lean LDS ----------
// One block (256 thr, 4 waves) per (g,b), grid 2048 XCD-swizzled.
// r12 lesson: 58KB LDS -> 2 blk/CU, VALU-bound at 22% occupancy. v2 drops the
// u staging (phase-1 A-operand read direct from global, scan u read with 1-deep
// prefetch) and overlays ddt on xd -> LDS 31.4KB -> 4-5 blk/CU.
// LDS: xln[49][40] bf16 @0 (3,920) | bcs[49][16] f32 @3,920 (3,136)
//   | R @7,056: xd[49][52] f32 (10,192; ph1-2) / ddt[49][256] bf16 (25,088; ph3-4)
__global__ __launch_bounds__(256) void k_xps(short* __restrict__ ycat,
    const short* __restrict__ xpw_bf, const float* __restrict__ lnw, const float* __restrict__ lnb,
    const short* __restrict__ dtw_bf, const float* __restrict__ dtb,
    const float* __restrict__ Alog, const float* __restrict__ Dp)
{
  __shared__ __align__(16) char smem[32144];
  short* xln = (short*)smem;                    // [49][40]
  float* bcs = (float*)(smem + 3920);           // [49][16]
  float* xd  = (float*)(smem + 7056);           // [49][52]  (phase 1-2)
  short* ddt = (short*)(smem + 7056);           // [49][256] (phase 3+, xd dead)

  int bid = blockIdx.x;                         // 2048 = 8 * 256, bijective XCD swizzle
  int swz = (bid & 7) * 256 + (bid >> 3);
  int g = swz >> 9, b = swz & 511;
  int tid = threadIdx.x, lane = tid & 63, w = tid >> 6;
  int mr = lane & 15, quad = lane >> 4, qk = quad * 8;

  // ---- phase 1: x_dbl = u @ xpw^T  (M=49 pad 64, N=48, K=256); A from global ----
  {
    int ar = w*16 + mr; if (ar > 48) ar = 48;        // clamp: rows >48 discarded
    const short* ap = ycat + (size_t)(b*49 + ar)*2048 + g*512 + qk;
    f32x4 acc[3] = {};
    #pragma unroll
    for (int k0 = 0; k0 < 256; k0 += 32){
      bf16x8 av = *(const bf16x8*)(ap + k0);
      #pragma unroll
      for (int t = 0; t < 3; ++t){
        bf16x8 bv = *(const bf16x8*)(xpw_bf + (t*16 + mr)*256 + qk + k0);
        acc[t] = __builtin_amdgcn_mfma_f32_16x16x32_bf16(av, bv, acc[t],0,0,0);
      }
    }
    #pragma unroll
    for (int t = 0; t < 3; ++t)
      #pragma unroll
      for (int r = 0; r < 4; ++r){
        int row = w*16 + quad*4 + r;
        if (row < 49) xd[row*52 + t*16 + mr] = acc[t][r];
      }
  }
  __syncthreads();

  // ---- phase 2: LN per row (threads 0..48) -> xln bf16 + bcs f32 ----
  if (tid < 49){
    f32x4* xr4 = (f32x4*)(xd + tid*52);
    f32x4 s = xr4[0];
    #pragma unroll
    for (int i=1;i<12;i++) s += xr4[i];
    float m = (s[0]+s[1]+s[2]+s[3]) * (1.f/48.f);
    f32x4 vs = {};
    #pragma unroll
    for (int i=0;i<12;i++){ f32x4 d = xr4[i] - m; vs += d*d; }
    float var = (vs[0]+vs[1]+vs[2]+vs[3]) * (1.f/48.f);
    float rstd = rsqrtf(var + 1e-5f);
    const f32x4* g4 = (const f32x4*)lnw;
    const f32x4* b4 = (const f32x4*)lnb;
    uint32_t* xlr = (uint32_t*)(xln + tid*40);
    #pragma unroll
    for (int i=0;i<8;i++){       // cols 0..31 -> xln bf16
      f32x4 v = (xr4[i] - m) * rstd * g4[i] + b4[i];
      xlr[2*i]   = (uint32_t)(uint16_t)f2bf(v[0]) | ((uint32_t)(uint16_t)f2bf(v[1]) << 16);
      xlr[2*i+1] = (uint32_t)(uint16_t)f2bf(v[2]) | ((uint32_t)(uint16_t)f2bf(v[3]) << 16);
    }
    f32x4* bco = (f32x4*)(bcs + tid*16);
    #pragma unroll
    for (int i=8;i<12;i++)       // cols 32..47 -> bcs f32
      bco[i-8] = (xr4[i] - m) * rstd * g4[i] + b4[i];
  }
  __syncthreads();               // xd dead from here; ddt may overwrite R

  // ---- phase 3: dt = xln[:,0:32] @ dtw^T (K=32, N=256) + bias + softplus -> ddt ----
  {
    int ar = w*16 + mr; if (ar > 48) ar = 48;
    bf16x8 a = *(const bf16x8*)(xln + ar*40 + qk);
    #pragma unroll 4
    for (int nt=0; nt<16; nt++){
      int col = nt*16 + mr;
      bf16x8 bv = *(const bf16x8*)(dtw_bf + col*32 + qk);
      float dtbv = dtb[col];
      f32x4 acc = {};
      acc = __builtin_amdgcn_mfma_f32_16x16x32_bf16(a, bv, acc,0,0,0);
      #pragma unroll
      for (int r=0;r<4;r++){
        int row = w*16 + quad*4 + r;
        if (row < 49){
          float dtv = acc[r] + dtbv;
          float e  = __expf(dtv);
          float sp = __logf(1.f + e);
          float delta = (dtv > 15.f) ? dtv : sp;
          ddt[row*256 + col] = f2bf(delta);
        }
      }
    }
  }
  __syncthreads();

  // ---- phase 4: selective scan (thread = channel d); u from global, 1-deep prefetch ----
  {
    int d = tid;
    float A[8], h[8];
    f32x4 a0 = *(const f32x4*)(Alog + d*8);
    f32x4 a1 = *(const f32x4*)(Alog + d*8 + 4);
    #pragma unroll
    for (int n=0;n<4;n++){ A[n] = -__expf(a0[n]); A[n+4] = -__expf(a1[n]); h[n]=0.f; h[n+4]=0.f; }
    float Dpar = Dp[d];
    short* uptr = ycat + (size_t)(b*49)*2048 + g*512 + d;

    float un = bf2f(uptr[0]);
    for (int l=0;l<49;l++){
      float u = un;
      if (l < 48) un = bf2f(uptr[(l+1)*2048]);
      float delta = bf2f(ddt[l*256 + d]);
      const f32x4* bcr = (const f32x4*)(bcs + l*16);
      f32x4 B0 = bcr[0], B1 = bcr[1], C0 = bcr[2], C1 = bcr[3];
      float du = delta * u;
      float y = 0.f;
      #pragma unroll
      for (int n=0;n<4;n++){
        h[n] = h[n]*__expf(delta*A[n]) + du*B0[n];
        y += h[n]*C0[n];
      }
      #pragma unroll
      for (int n=0;n<4;n++){
        h[n+4] = h[n+4]*__expf(delta*A[n+4]) + du*B1[n];
        y += h[n+4]*C1[n];
      }
      uptr[l*2048] = f2bf(y + Dpar*u);
    }
  }
}

// ---------- final GEMM: 256x128 tile, BK=32, K=2048 (NT=64), grid 392, XCD-swz ----------
__global__ __launch_bounds__(512) void k_gemmF(const short* __restrict__ ycat,
    const short* __restrict__ wogc, const float* __restrict__ biasc,
    float* __restrict__ out)
{
  __shared__ __align__(16) short S[24576];    // 48 KB: 2 buf x (A 16KB | B 8KB)
  int bid = blockIdx.x;                       // 392 = 8 * 49, bijective XCD swizzle
  int swz = (bid & 7) * 49 + (bid >> 3);
  int bm = (swz >> 2) * 256, bn = (swz & 3) * 128;
  int tid = threadIdx.x, lane = tid & 63, w = tid >> 6;

  int rl = lane >> 2;                                 // row within 16-row unit
  int gch = ((lane & 3) ^ ((lane >> 3) & 3)) * 8;     // pre-swizzled global chunk
  const short* aU0 = ycat + (size_t)(bm + w*32      + rl)*2048 + gch;
  const short* aU1 = ycat + (size_t)(bm + w*32 + 16 + rl)*2048 + gch;
  const short* bU  = wogc + (size_t)(bn + w*16      + rl)*2048 + gch;

  f32x4 acc[4][4] = {};
  kcore256x128<64>(aU0, aU1, bU, S, w, lane, acc);

  int wr = w >> 1, wc = w & 1, mr = lane & 15, quad = lane >> 4;
  #pragma unroll
  for (int mf = 0; mf < 4; ++mf)
    #pragma unroll
    for (int rr = 0; rr < 4; ++rr){
      int row = bm + wr*64 + mf*16 + quad*4 + rr;
      float* orow = out + (size_t)row*512;
      #pragma unroll
      for (int nf = 0; nf < 4; ++nf){
        int col = bn + wc*64 + nf*16 + mr;
        orow[col] = acc[mf][nf][rr] + biasc[col];
      }
    }
}

// ---------- launch ----------
extern "C" void kernel_launch(void* const* d_in, const int* in_sizes, int n_in,
                              void* d_out, int out_size, void* d_ws, size_t ws_size,
                              hipStream_t stream)
{
  const float* tokens    = (const float*)d_in[0];
  const float* pre_w[4]  = {(const float*)d_in[1], (const float*)d_in[3], (const float*)d_in[5], (const float*)d_in[7]};
  const float* pre_b[4]  = {(const float*)d_in[2], (const float*)d_in[4], (const float*)d_in[6], (const float*)d_in[8]};
  const float* post_w[4] = {(const float*)d_in[9], (const float*)d_in[11], (const float*)d_in[13], (const float*)d_in[15]};
  const float* post_b[4] = {(const float*)d_in[10], (const float*)d_in[12], (const float*)d_in[14], (const float*)d_in[16]};
  const float* in_proj   = (const float*)d_in[17];
  const float* conv_x_w  = (const float*)d_in[18];
  const float* conv_x_b  = (const float*)d_in[19];
  const float* conv_z_w  = (const float*)d_in[20];
  const float* conv_z_b  = (const float*)d_in[21];
  const float* x_proj_w  = (const float*)d_in[22];
  const float* ln_w      = (const float*)d_in[23];
  const float* ln_b      = (const float*)d_in[24];
  const float* dt_proj_w = (const float*)d_in[25];
  const float* dt_proj_b = (const float*)d_in[26];
  const float* A_log     = (const float*)d_in[27];
  const float* D_param   = (const float*)d_in[28];
  const float* out_proj  = (const float*)d_in[29];
  const float* gate_log  = (const float*)d_in[30];

  char* ws = (char*)d_ws;
  size_t o = 0;
  short* tok_bf   = (short*)(ws + o); o += 25690112;   // 12845056 bf16
  short* wpreT    = (short*)(ws + o); o += 2097152;    // 4x 512x512 bf16 (transposed)
  short* inp_bf   = (short*)(ws + o); o += 524288;
  short* postw_bf = (short*)(ws + o); o += 2097152;
  short* woutT    = (short*)(ws + o); o += 524288;
  short* wogc     = (short*)(ws + o); o += 2097152;    // 512 x 2048 bf16
  short* wxz      = (short*)(ws + o); o += 2097152;    // 4x 512x512 bf16
  short* xpw_bf   = (short*)(ws + o); o += 24576;      // 48x256 bf16
  short* dtw_bf   = (short*)(ws + o); o += 16384;      // 256x32 bf16
  float* bxz      = (float*)(ws + o); o += 8192;
  float* gains    = (float*)(ws + o); o += 64;
  float* biasc    = (float*)(ws + o); o += 2048;
  size_t scratch_off = o;
  o += 102760448;                                      // (unused; kept for layout stability)
  short* ycat     = (short*)(ws + o); o += 102760448;  // 25088 x 2048 bf16
  (void)scratch_off;

  k_conv_all<<<1300, 256, 0, stream>>>(in_proj,
      post_w[0], post_w[1], post_w[2], post_w[3],
      x_proj_w, dt_proj_w, inp_bf, postw_bf, xpw_bf, dtw_bf);
  k_transp<<<dim3(64,5), 256, 0, stream>>>(pre_w[0], pre_w[1], pre_w[2], pre_w[3],
      out_proj, wpreT, woutT);
  k_tok<<<12544, 256, 0, stream>>>(tokens, tok_bf);
  k_bxz_gains<<<9, 256, 0, stream>>>(in_proj, pre_b[0], pre_b[1], pre_b[2], pre_b[3],
      gate_log, post_b[0], post_b[1], post_b[2], post_b[3], bxz, gains, biasc);
  k_wfuse<<<dim3(8,4,8), 256, 0, stream>>>(inp_bf, wpreT, postw_bf, woutT, gains, wxz, wogc);
  k_gemm1c<<<dim3(1648), 512, 0, stream>>>(tok_bf, wxz, bxz,
      conv_x_w, conv_x_b, conv_z_w, conv_z_b, ycat);
  k_xps<<<dim3(2048), 256, 0, stream>>>(ycat, xpw_bf, ln_w, ln_b,
      dtw_bf, dt_proj_b, A_log, D_param);
  k_gemmF<<<dim3(392), 512, 0, stream>>>(ycat, wogc, biasc, (float*)d_out);
}